// Round 10
// baseline (131.137 us; speedup 1.0000x reference)
//
#include <hip/hip_runtime.h>
#include <stdint.h>

typedef unsigned long long u64;

#define N 8192
#define NW 128            // 64-bit words per mask row
#define MAX_OUT 256
#define MASK_BYTES ((size_t)N * NW * 8)   // 8 MiB

// ws layout:
//   [0, 8MB)    maskT u64[NW][N]  (column-major: maskT[w*N + i])
//   +8MB        order  int[N]     32 KB
//   +32KB       s_s    float[N]   32 KB
//   +64KB       bbox   float4[N] 128 KB
//   +192KB      area   float[N]   32 KB
//   +224KB      nvalid int
// No init needed anywhere (rank is a permutation; maskT garbage only in
// never-consumed positions; nvalid written each launch).

// ========== Kernel 1: fused rank + scatter + nvalid (no atomics, no init) ====
__global__ __launch_bounds__(1024)
void rank_fused_kernel(const float* __restrict__ score, const float* __restrict__ box,
                       int* __restrict__ order, float* __restrict__ s_s,
                       float4* __restrict__ bbox, float* __restrict__ area,
                       int* __restrict__ nvalid) {
    __shared__ uint32_t ksc[N];        // 32 KB: all score bit-patterns
    __shared__ int psum[32][33];       // +1 pad
    __shared__ int vpart[16];
    const int tid = threadIdx.x;

    const float4* s4 = (const float4*)score;
    float4 a = s4[tid * 2], b = s4[tid * 2 + 1];
    ksc[tid * 8 + 0] = __float_as_uint(a.x);
    ksc[tid * 8 + 1] = __float_as_uint(a.y);
    ksc[tid * 8 + 2] = __float_as_uint(a.z);
    ksc[tid * 8 + 3] = __float_as_uint(a.w);
    ksc[tid * 8 + 4] = __float_as_uint(b.x);
    ksc[tid * 8 + 5] = __float_as_uint(b.y);
    ksc[tid * 8 + 6] = __float_as_uint(b.z);
    ksc[tid * 8 + 7] = __float_as_uint(b.w);
    int c = (a.x >= 0.3f) + (a.y >= 0.3f) + (a.z >= 0.3f) + (a.w >= 0.3f)
          + (b.x >= 0.3f) + (b.y >= 0.3f) + (b.z >= 0.3f) + (b.w >= 0.3f);
    for (int off = 32; off; off >>= 1) c += __shfl_down(c, off);
    if ((tid & 63) == 0) vpart[tid >> 6] = c;
    __syncthreads();
    if (blockIdx.x == 0 && tid == 0) {
        int t = 0;
        #pragma unroll
        for (int w = 0; w < 16; ++w) t += vpart[w];
        *nvalid = t;
    }

    const int i_local = tid & 31;
    const int jg = tid >> 5;
    const int ibase = blockIdx.x * 32;
    const uint32_t si = ksc[ibase + i_local];
    const int i = ibase + i_local;
    int cnt = 0;
    const int j0 = jg * 256;
    #pragma unroll 8
    for (int t = 0; t < 256; ++t) {
        const int j = j0 + t;
        const uint32_t sj = ksc[j];
        cnt += (sj > si || (sj == si && j < i)) ? 1 : 0;
    }
    psum[i_local][jg] = cnt;
    __syncthreads();

    if (tid < 32) {
        int r = 0;
        #pragma unroll
        for (int k = 0; k < 32; ++k) r += psum[tid][k];
        const int ii = ibase + tid;
        order[r] = ii;
        s_s[r] = score[ii];
        float4 cb = ((const float4*)box)[ii * 4];   // first 4 of 16: cx,cy,w,h
        float hw = cb.z * 0.5f, hh = cb.w * 0.5f;
        float x0 = cb.x - hw, y0 = cb.y - hh, x1 = cb.x + hw, y1 = cb.y + hh;
        bbox[r] = make_float4(x0, y0, x1, y1);
        area[r] = (x1 - x0) * (y1 - y0);            // replicate ref: area from xyxy
    }
}

// ========== Kernel 2: suppression bitmask, column-major, div-free fast path ==
__global__ __launch_bounds__(256)
void mask_kernel(const float4* __restrict__ bbox, const float* __restrict__ area,
                 const int* __restrict__ nvalid_p, u64* __restrict__ maskT) {
    const int w = blockIdx.x;
    if (w < (int)(blockIdx.y << 2)) return;          // whole block below diagonal
    const int nv = *nvalid_p;
    if ((int)(blockIdx.y * 256) >= nv) return;
    __shared__ float4 jb[64];
    __shared__ float  ja[64];
    if (threadIdx.x < 64) {
        jb[threadIdx.x] = bbox[w * 64 + threadIdx.x];
        ja[threadIdx.x] = area[w * 64 + threadIdx.x];
    }
    __syncthreads();
    const int i = blockIdx.y * 256 + threadIdx.x;
    if (i >= nv) return;
    if (w < (i >> 6)) return;
    float4 aa4 = bbox[i];
    float  aa = area[i];
    u64 bits = 0, fb = 0;
    #pragma unroll 8
    for (int jj = 0; jj < 64; ++jj) {
        float4 b = jb[jj];
        float lx = fmaxf(aa4.x, b.x), ly = fmaxf(aa4.y, b.y);
        float rx = fminf(aa4.z, b.z), ry = fminf(aa4.w, b.w);
        float ww = fmaxf(rx - lx, 0.0f), hh = fmaxf(ry - ly, 0.0f);
        float inter = ww * hh;
        float denom = ((aa + ja[jj]) - inter) + 1e-9f;  // exact ref op order
        float d = fmaf(-0.3f, denom, inter);            // sign decides iou>0.3
        bits |= ((u64)(d > 0.0f)) << jj;
        fb   |= ((u64)(fabsf(d) <= 1e-5f * denom)) << jj;
    }
    if (fb) {   // rare exact-divide fixup (margin 1e-5 >> ulp(0.3f)~3e-8)
        while (fb) {
            int jj = (int)__builtin_ctzll(fb); fb &= fb - 1;
            float4 b = jb[jj];
            float lx = fmaxf(aa4.x, b.x), ly = fmaxf(aa4.y, b.y);
            float rx = fminf(aa4.z, b.z), ry = fminf(aa4.w, b.w);
            float ww = fmaxf(rx - lx, 0.0f), hh = fmaxf(ry - ly, 0.0f);
            float inter = ww * hh;
            float denom = ((aa + ja[jj]) - inter) + 1e-9f;
            float iou = inter / denom;                   // IEEE div, matches np
            bits = (bits & ~(1ull << jj)) | (((u64)(iou > 0.3f)) << jj);
        }
    }
    maskT[(size_t)w * N + i] = bits;                     // coalesced
}

// ========== Kernel 3: serial greedy — 128-row steps, 2-step-deep pipeline ====
// Step t covers blocks w0=2t, w1=2t+1. Pipe set for step t is issued at the
// TOP of step t-2 (two full steps of slack ≈ 1600-2600 cy covers IF$/HBM
// latency after the inter-kernel flush; R8/R9's 1-step slack did not — the
// measured 2133 cy/step was a per-step latency stall, not spill: VGPR=40 with
// launch_bounds(64,1) proved the 1-deep pipe fits registers).
// Gathers issued at t-2 know kept through t-3 => TWO carry generations:
//   spec1 = cols 2t+2,2t+3 over step-t rows -> c1n (consumed at t+1)
//   spec2 = cols 2t+4,2t+5 over step-t rows -> c2n (pending, consumed at t+2)
// In-step coupling unchanged: low-block ballot(c00), low->high via
// readlane(c10, l), high-block ballot(c11).
// Per-set pipe: 3 cols + 8 specs + 8 gathers = 19 u64; two sets in flight.

__device__ __forceinline__ unsigned or_dpp32(unsigned v) {
    v |= (unsigned)__builtin_amdgcn_update_dpp(0, (int)v, 0x111, 0xf, 0xf, true); // row_shr:1
    v |= (unsigned)__builtin_amdgcn_update_dpp(0, (int)v, 0x112, 0xf, 0xf, true); // row_shr:2
    v |= (unsigned)__builtin_amdgcn_update_dpp(0, (int)v, 0x114, 0xf, 0xf, true); // row_shr:4
    v |= (unsigned)__builtin_amdgcn_update_dpp(0, (int)v, 0x118, 0xf, 0xf, true); // row_shr:8
    v |= (unsigned)__builtin_amdgcn_update_dpp(0, (int)v, 0x142, 0xf, 0xf, true); // row_bcast:15
    v |= (unsigned)__builtin_amdgcn_update_dpp(0, (int)v, 0x143, 0xf, 0xf, true); // row_bcast:31
    return v;
}

__device__ __forceinline__ u64 wave_or64(u64 v) {
    unsigned lo = or_dpp32((unsigned)v);
    unsigned hi = or_dpp32((unsigned)(v >> 32));
    unsigned slo = (unsigned)__builtin_amdgcn_readlane((int)lo, 63);
    unsigned shi = (unsigned)__builtin_amdgcn_readlane((int)hi, 63);
    return ((u64)shi << 32) | (u64)slo;
}

#define RL64(v, l) ( ((u64)(unsigned)__builtin_amdgcn_readlane((int)(unsigned)((v) >> 32), (l)) << 32) \
                   |  (u64)(unsigned)__builtin_amdgcn_readlane((int)(unsigned)(v), (l)) )

// One 128-row step. Consumes pipe set {PC..,S..,G..,H..} (loaded 2 steps ago),
// reissues the same set for step T+2, resolves, updates carries.
#define NMS_STEP(T, PC00,PC10,PC11, S1A0,S1A1,S1B0,S1B1, S2A0,S2A1,S2B0,S2B1,  \
                 G0,G1,G2,G3, H0,H1,H2,H3) do {                                \
    const int t_ = (T);                                                        \
    /* consume (SSA renames; waitcnt lands at first real use) */               \
    u64 c00_ = PC00, c10_ = PC10, c11_ = PC11;                                 \
    u64 x0_ = G0 | G1 | G2 | G3 | carry1_0 | carry2_0;                         \
    u64 x1_ = H0 | H1 | H2 | H3 | carry1_1 | carry2_1;                         \
    u64 s1a0_=S1A0, s1a1_=S1A1, s1b0_=S1B0, s1b1_=S1B1;                        \
    u64 s2a0_=S2A0, s2a1_=S2A1, s2b0_=S2B0, s2b1_=S2B1;                        \
    /* reissue this set for step T+2 (kcount/kp cover kept through T-1) */     \
    PC00=0; PC10=0; PC11=0;                                                    \
    S1A0=0; S1A1=0; S1B0=0; S1B1=0; S2A0=0; S2A1=0; S2B0=0; S2B1=0;            \
    G0=0; G1=0; G2=0; G3=0; H0=0; H1=0; H2=0; H3=0;                            \
    const int t2_ = t_ + 2;                                                    \
    if (t2_ < nst) {                                                           \
        const int w0n_ = t2_ << 1, w1n_ = w0n_ | 1;                            \
        const size_t r0_ = ((size_t)t2_ << 7) + lane;                          \
        const u64* cw0_ = maskT + (size_t)w0n_ * N;                            \
        const int kc_ = kcount;                                                \
        PC00 = cw0_[r0_];                                                      \
        if (lane < kc_)        G0 = cw0_[kp0];                                 \
        if (lane +  64 < kc_)  G1 = cw0_[kp1];                                 \
        if (lane + 128 < kc_)  G2 = cw0_[kp2];                                 \
        if (lane + 192 < kc_)  G3 = cw0_[kp3];                                 \
        if (w1n_ < nblk) {                                                     \
            const u64* cw1_ = maskT + (size_t)w1n_ * N;                        \
            PC10 = cw1_[r0_];                                                  \
            PC11 = cw1_[r0_ + 64];                                             \
            if (lane < kc_)        H0 = cw1_[kp0];                             \
            if (lane +  64 < kc_)  H1 = cw1_[kp1];                             \
            if (lane + 128 < kc_)  H2 = cw1_[kp2];                             \
            if (lane + 192 < kc_)  H3 = cw1_[kp3];                             \
        }                                                                      \
        if (w0n_ + 2 < nblk) { const u64* p_ = maskT + (size_t)(w0n_+2)*N;     \
                               S1A0 = p_[r0_]; S1A1 = p_[r0_ + 64]; }          \
        if (w0n_ + 3 < nblk) { const u64* p_ = maskT + (size_t)(w0n_+3)*N;     \
                               S1B0 = p_[r0_]; S1B1 = p_[r0_ + 64]; }          \
        if (w0n_ + 4 < nblk) { const u64* p_ = maskT + (size_t)(w0n_+4)*N;     \
                               S2A0 = p_[r0_]; S2A1 = p_[r0_ + 64]; }          \
        if (w0n_ + 5 < nblk) { const u64* p_ = maskT + (size_t)(w0n_+5)*N;     \
                               S2B0 = p_[r0_]; S2B1 = p_[r0_ + 64]; }          \
    }                                                                          \
    /* suppression words: two independent DPP reduces */                       \
    u64 rw0_ = wave_or64(x0_);                                                 \
    u64 rw1_ = wave_or64(x1_);                                                 \
    const int base_ = t_ << 7;                                                 \
    const int rem0_ = nv - base_;                                              \
    const int rem1_ = rem0_ - 64;                                              \
    u64 vm0_ = (rem0_ >= 64) ? ~0ull : ((1ull << rem0_) - 1ull);               \
    u64 vm1_ = (rem1_ >= 64) ? ~0ull : ((rem1_ > 0) ? ((1ull << rem1_) - 1ull) : 0ull); \
    u64 km0_ = 0, km1_ = 0;                                                    \
    u64 todo_ = vm0_ & ~rw0_;                                                  \
    while (todo_) {                                                            \
        int l_ = (int)__builtin_ctzll(todo_);                                  \
        u64 rowl_ = __ballot(((c00_ >> l_) & 1ull) != 0);                      \
        const int pos_ = base_ + l_;                                           \
        const bool own_ = (lane == (kcount & 63));                             \
        const int slot_ = kcount >> 6;                                         \
        kp0 = (own_ && slot_ == 0) ? pos_ : kp0;                               \
        kp1 = (own_ && slot_ == 1) ? pos_ : kp1;                               \
        kp2 = (own_ && slot_ == 2) ? pos_ : kp2;                               \
        kp3 = (own_ && slot_ == 3) ? pos_ : kp3;                               \
        km0_ |= 1ull << l_;                                                    \
        kcount++;                                                              \
        todo_ &= ~(rowl_ | (1ull << l_));                                      \
        rw1_ |= RL64(c10_, l_);                                                \
        if (kcount >= MAX_OUT) break;                                          \
    }                                                                          \
    if (kcount < MAX_OUT) {                                                    \
        todo_ = vm1_ & ~rw1_;                                                  \
        while (todo_) {                                                        \
            int l_ = (int)__builtin_ctzll(todo_);                              \
            u64 rowl_ = __ballot(((c11_ >> l_) & 1ull) != 0);                  \
            const int pos_ = base_ + 64 + l_;                                  \
            const bool own_ = (lane == (kcount & 63));                         \
            const int slot_ = kcount >> 6;                                     \
            kp0 = (own_ && slot_ == 0) ? pos_ : kp0;                           \
            kp1 = (own_ && slot_ == 1) ? pos_ : kp1;                           \
            kp2 = (own_ && slot_ == 2) ? pos_ : kp2;                           \
            kp3 = (own_ && slot_ == 3) ? pos_ : kp3;                           \
            km1_ |= 1ull << l_;                                                \
            kcount++;                                                          \
            todo_ &= ~(rowl_ | (1ull << l_));                                  \
            if (kcount >= MAX_OUT) break;                                      \
        }                                                                      \
    }                                                                          \
    /* carries: gen1 (consumed next step) + gen2 (pending, step after) */      \
    u64 keepm0_ = ((km0_ >> lane) & 1ull) ? ~0ull : 0ull;                      \
    u64 keepm1_ = ((km1_ >> lane) & 1ull) ? ~0ull : 0ull;                      \
    carry1_0 = (s1a0_ & keepm0_) | (s1a1_ & keepm1_);                          \
    carry1_1 = (s1b0_ & keepm0_) | (s1b1_ & keepm1_);                          \
    carry2_0 = c2pend0; carry2_1 = c2pend1;                                    \
    c2pend0 = (s2a0_ & keepm0_) | (s2a1_ & keepm1_);                           \
    c2pend1 = (s2b0_ & keepm0_) | (s2b1_ & keepm1_);                           \
} while (0)

__global__ __launch_bounds__(64, 1)
void nms_kernel(const u64* __restrict__ maskT, const float* __restrict__ s_s,
                const int* __restrict__ order, const float* __restrict__ box,
                const int* __restrict__ nvalid_p, float* __restrict__ out) {
    const int lane = threadIdx.x;
    const int nv = *nvalid_p;
    const int nblk = (nv + 63) >> 6;
    const int nst = (nblk + 1) >> 1;
    int kcount = 0;
    int kp0 = 0, kp1 = 0, kp2 = 0, kp3 = 0;   // kept idx slots lane, 64+l, 128+l, 192+l
    u64 carry1_0 = 0, carry1_1 = 0;           // from kept at t-1
    u64 carry2_0 = 0, carry2_1 = 0;           // from kept at t-2
    u64 c2pend0 = 0, c2pend1 = 0;             // staged gen2

    // pipe set A (step 0) and B (step 1)
    u64 apc00=0, apc10=0, apc11=0;
    u64 as1a0=0, as1a1=0, as1b0=0, as1b1=0, as2a0=0, as2a1=0, as2b0=0, as2b1=0;
    u64 ag0=0, ag1=0, ag2=0, ag3=0, ah0=0, ah1=0, ah2=0, ah3=0;
    u64 bpc00=0, bpc10=0, bpc11=0;
    u64 bs1a0=0, bs1a1=0, bs1b0=0, bs1b1=0, bs2a0=0, bs2a1=0, bs2b0=0, bs2b1=0;
    u64 bg0=0, bg1=0, bg2=0, bg3=0, bh0=0, bh1=0, bh2=0, bh3=0;

    // prologue: prime A for step 0, B for step 1 (no gathers: kcount==0)
    if (nst > 0) {
        const size_t r0 = (size_t)lane;
        apc00 = maskT[r0];
        if (1 < nblk) { apc10 = maskT[(size_t)1*N + r0]; apc11 = maskT[(size_t)1*N + r0 + 64]; }
        if (2 < nblk) { as1a0 = maskT[(size_t)2*N + r0]; as1a1 = maskT[(size_t)2*N + r0 + 64]; }
        if (3 < nblk) { as1b0 = maskT[(size_t)3*N + r0]; as1b1 = maskT[(size_t)3*N + r0 + 64]; }
        if (4 < nblk) { as2a0 = maskT[(size_t)4*N + r0]; as2a1 = maskT[(size_t)4*N + r0 + 64]; }
        if (5 < nblk) { as2b0 = maskT[(size_t)5*N + r0]; as2b1 = maskT[(size_t)5*N + r0 + 64]; }
    }
    if (1 < nst) {
        const size_t r1 = (size_t)128 + lane;
        bpc00 = maskT[(size_t)2*N + r1];
        if (3 < nblk) { bpc10 = maskT[(size_t)3*N + r1]; bpc11 = maskT[(size_t)3*N + r1 + 64]; }
        if (4 < nblk) { bs1a0 = maskT[(size_t)4*N + r1]; bs1a1 = maskT[(size_t)4*N + r1 + 64]; }
        if (5 < nblk) { bs1b0 = maskT[(size_t)5*N + r1]; bs1b1 = maskT[(size_t)5*N + r1 + 64]; }
        if (6 < nblk) { bs2a0 = maskT[(size_t)6*N + r1]; bs2a1 = maskT[(size_t)6*N + r1 + 64]; }
        if (7 < nblk) { bs2b0 = maskT[(size_t)7*N + r1]; bs2b1 = maskT[(size_t)7*N + r1 + 64]; }
    }

    for (int t = 0; t < nst && kcount < MAX_OUT; t += 2) {
        NMS_STEP(t, apc00,apc10,apc11, as1a0,as1a1,as1b0,as1b1,
                 as2a0,as2a1,as2b0,as2b1, ag0,ag1,ag2,ag3, ah0,ah1,ah2,ah3);
        if (t + 1 < nst && kcount < MAX_OUT)
            NMS_STEP(t + 1, bpc00,bpc10,bpc11, bs1a0,bs1a1,bs1b0,bs1b1,
                     bs2a0,bs2a1,bs2b0,bs2b1, bg0,bg1,bg2,bg3, bh0,bh1,bh2,bh3);
    }

    // outputs: [score 256][box 256*16][valid 256], all float32
    float* out_score = out;
    float* out_box   = out + MAX_OUT;
    float* out_valid = out + MAX_OUT + MAX_OUT * 16;
    const float4* box4 = (const float4*)box;
    float4* ob4 = (float4*)out_box;
    #define EMIT_SLOT(Q, KP) do {                                              \
        const int t = lane + 64 * (Q);                                         \
        if (t < kcount) {                                                      \
            int p = (KP);                                                      \
            out_score[t] = s_s[p];                                             \
            out_valid[t] = 1.0f;                                               \
            int oi = order[p];                                                 \
            _Pragma("unroll")                                                  \
            for (int q = 0; q < 4; ++q) ob4[t * 4 + q] = box4[oi * 4 + q];     \
        } else {                                                               \
            out_score[t] = 0.0f;                                               \
            out_valid[t] = 0.0f;                                               \
            float4 z = make_float4(0.f, 0.f, 0.f, 0.f);                        \
            _Pragma("unroll")                                                  \
            for (int q = 0; q < 4; ++q) ob4[t * 4 + q] = z;                    \
        }                                                                      \
    } while (0)
    EMIT_SLOT(0, kp0);
    EMIT_SLOT(1, kp1);
    EMIT_SLOT(2, kp2);
    EMIT_SLOT(3, kp3);
    #undef EMIT_SLOT
}

extern "C" void kernel_launch(void* const* d_in, const int* in_sizes, int n_in,
                              void* d_out, int out_size, void* d_ws, size_t ws_size,
                              hipStream_t stream) {
    const float* score = (const float*)d_in[0];   // (8192,1) f32
    const float* box   = (const float*)d_in[1];   // (8192,16) f32
    char* ws = (char*)d_ws;
    u64*    maskT  = (u64*)ws;
    int*    order  = (int*)   (ws + MASK_BYTES);
    float*  s_s    = (float*) (ws + MASK_BYTES + 32768);
    float4* bbox   = (float4*)(ws + MASK_BYTES + 65536);
    float*  area   = (float*) (ws + MASK_BYTES + 65536 + 131072);
    int*    nvalid = (int*)   (ws + MASK_BYTES + 65536 + 131072 + 32768);

    rank_fused_kernel<<<256, 1024, 0, stream>>>(score, box, order, s_s, bbox, area, nvalid);
    mask_kernel<<<dim3(128, 32), 256, 0, stream>>>(bbox, area, nvalid, maskT);
    nms_kernel<<<1, 64, 0, stream>>>(maskT, s_s, order, box, nvalid, (float*)d_out);
}

// Round 11
// 126.046 us; speedup vs baseline: 1.0404x; 1.0404x over previous
//
#include <hip/hip_runtime.h>
#include <stdint.h>

typedef unsigned long long u64;

#define N 8192
#define NW 128            // 64-bit words per mask row
#define MAX_OUT 256
#define MASK_BYTES ((size_t)N * NW * 8)   // 8 MiB

// ws layout:
//   [0, 8MB)    maskT u64[NW][N]  (column-major: maskT[w*N + i])
//   +8MB        order  int[N]     32 KB
//   +32KB       s_s    float[N]   32 KB
//   +64KB       bbox   float4[N] 128 KB
//   +192KB      area   float[N]   32 KB
//   +224KB      nvalid int
// No init needed anywhere (rank is a permutation; maskT garbage only in
// never-consumed positions; nvalid written each launch).

// ========== Kernel 1: fused rank + scatter + nvalid (no atomics, no init) ====
__global__ __launch_bounds__(1024)
void rank_fused_kernel(const float* __restrict__ score, const float* __restrict__ box,
                       int* __restrict__ order, float* __restrict__ s_s,
                       float4* __restrict__ bbox, float* __restrict__ area,
                       int* __restrict__ nvalid) {
    __shared__ uint32_t ksc[N];        // 32 KB: all score bit-patterns
    __shared__ int psum[32][33];       // +1 pad
    __shared__ int vpart[16];
    const int tid = threadIdx.x;

    const float4* s4 = (const float4*)score;
    float4 a = s4[tid * 2], b = s4[tid * 2 + 1];
    ksc[tid * 8 + 0] = __float_as_uint(a.x);
    ksc[tid * 8 + 1] = __float_as_uint(a.y);
    ksc[tid * 8 + 2] = __float_as_uint(a.z);
    ksc[tid * 8 + 3] = __float_as_uint(a.w);
    ksc[tid * 8 + 4] = __float_as_uint(b.x);
    ksc[tid * 8 + 5] = __float_as_uint(b.y);
    ksc[tid * 8 + 6] = __float_as_uint(b.z);
    ksc[tid * 8 + 7] = __float_as_uint(b.w);
    int c = (a.x >= 0.3f) + (a.y >= 0.3f) + (a.z >= 0.3f) + (a.w >= 0.3f)
          + (b.x >= 0.3f) + (b.y >= 0.3f) + (b.z >= 0.3f) + (b.w >= 0.3f);
    for (int off = 32; off; off >>= 1) c += __shfl_down(c, off);
    if ((tid & 63) == 0) vpart[tid >> 6] = c;
    __syncthreads();
    if (blockIdx.x == 0 && tid == 0) {
        int t = 0;
        #pragma unroll
        for (int w = 0; w < 16; ++w) t += vpart[w];
        *nvalid = t;
    }

    const int i_local = tid & 31;
    const int jg = tid >> 5;
    const int ibase = blockIdx.x * 32;
    const uint32_t si = ksc[ibase + i_local];
    const int i = ibase + i_local;
    int cnt = 0;
    const int j0 = jg * 256;
    #pragma unroll 8
    for (int t = 0; t < 256; ++t) {
        const int j = j0 + t;
        const uint32_t sj = ksc[j];
        cnt += (sj > si || (sj == si && j < i)) ? 1 : 0;
    }
    psum[i_local][jg] = cnt;
    __syncthreads();

    if (tid < 32) {
        int r = 0;
        #pragma unroll
        for (int k = 0; k < 32; ++k) r += psum[tid][k];
        const int ii = ibase + tid;
        order[r] = ii;
        s_s[r] = score[ii];
        float4 cb = ((const float4*)box)[ii * 4];   // first 4 of 16: cx,cy,w,h
        float hw = cb.z * 0.5f, hh = cb.w * 0.5f;
        float x0 = cb.x - hw, y0 = cb.y - hh, x1 = cb.x + hw, y1 = cb.y + hh;
        bbox[r] = make_float4(x0, y0, x1, y1);
        area[r] = (x1 - x0) * (y1 - y0);            // replicate ref: area from xyxy
    }
}

// ========== Kernel 2: suppression bitmask, column-major, div-free fast path ==
__global__ __launch_bounds__(256)
void mask_kernel(const float4* __restrict__ bbox, const float* __restrict__ area,
                 const int* __restrict__ nvalid_p, u64* __restrict__ maskT) {
    const int w = blockIdx.x;
    if (w < (int)(blockIdx.y << 2)) return;          // whole block below diagonal
    const int nv = *nvalid_p;
    if ((int)(blockIdx.y * 256) >= nv) return;
    __shared__ float4 jb[64];
    __shared__ float  ja[64];
    if (threadIdx.x < 64) {
        jb[threadIdx.x] = bbox[w * 64 + threadIdx.x];
        ja[threadIdx.x] = area[w * 64 + threadIdx.x];
    }
    __syncthreads();
    const int i = blockIdx.y * 256 + threadIdx.x;
    if (i >= nv) return;
    if (w < (i >> 6)) return;
    float4 aa4 = bbox[i];
    float  aa = area[i];
    u64 bits = 0, fb = 0;
    #pragma unroll 8
    for (int jj = 0; jj < 64; ++jj) {
        float4 b = jb[jj];
        float lx = fmaxf(aa4.x, b.x), ly = fmaxf(aa4.y, b.y);
        float rx = fminf(aa4.z, b.z), ry = fminf(aa4.w, b.w);
        float ww = fmaxf(rx - lx, 0.0f), hh = fmaxf(ry - ly, 0.0f);
        float inter = ww * hh;
        float denom = ((aa + ja[jj]) - inter) + 1e-9f;  // exact ref op order
        float d = fmaf(-0.3f, denom, inter);            // sign decides iou>0.3
        bits |= ((u64)(d > 0.0f)) << jj;
        fb   |= ((u64)(fabsf(d) <= 1e-5f * denom)) << jj;
    }
    if (fb) {   // rare exact-divide fixup (margin 1e-5 >> ulp(0.3f)~3e-8)
        while (fb) {
            int jj = (int)__builtin_ctzll(fb); fb &= fb - 1;
            float4 b = jb[jj];
            float lx = fmaxf(aa4.x, b.x), ly = fmaxf(aa4.y, b.y);
            float rx = fminf(aa4.z, b.z), ry = fminf(aa4.w, b.w);
            float ww = fmaxf(rx - lx, 0.0f), hh = fmaxf(ry - ly, 0.0f);
            float inter = ww * hh;
            float denom = ((aa + ja[jj]) - inter) + 1e-9f;
            float iou = inter / denom;                   // IEEE div, matches np
            bits = (bits & ~(1ull << jj)) | (((u64)(iou > 0.3f)) << jj);
        }
    }
    maskT[(size_t)w * N + i] = bits;                     // coalesced
}

// ========== Kernel 3: serial greedy (R7 structure, UNCONDITIONAL pipe loads) =
// R10 evidence: conditional pipe loads force the compiler's conservative
// s_waitcnt vmcnt(0) at each consume (outstanding count indeterminate across
// execz-skippable branches) -> any software pipeline collapses to ~1-step
// slack. Fix: every load always issues (clamped addresses: min(word, nblk-1);
// kp* default 0 -> always-valid gather addresses). Range/validity masking is
// applied at CONSUME (post-wait), never at issue. Gather validity uses the
// issue-time snapshot P.kc, preserving exact R5/R7 semantics:
// at consume step c: gathers cover kept <= c-3, s1m = kept at c-1,
// s2m_old = kept at c-2, diagonal via ballot symmetry.
struct Pipe { u64 col, s1, s2, g0, g1, g2, g3; int kc; };

__device__ __forceinline__ unsigned or_dpp32(unsigned v) {
    v |= (unsigned)__builtin_amdgcn_update_dpp(0, (int)v, 0x111, 0xf, 0xf, true); // row_shr:1
    v |= (unsigned)__builtin_amdgcn_update_dpp(0, (int)v, 0x112, 0xf, 0xf, true); // row_shr:2
    v |= (unsigned)__builtin_amdgcn_update_dpp(0, (int)v, 0x114, 0xf, 0xf, true); // row_shr:4
    v |= (unsigned)__builtin_amdgcn_update_dpp(0, (int)v, 0x118, 0xf, 0xf, true); // row_shr:8
    v |= (unsigned)__builtin_amdgcn_update_dpp(0, (int)v, 0x142, 0xf, 0xf, true); // row_bcast:15
    v |= (unsigned)__builtin_amdgcn_update_dpp(0, (int)v, 0x143, 0xf, 0xf, true); // row_bcast:31
    return v;
}

__device__ __forceinline__ u64 wave_or64(u64 v) {
    unsigned lo = or_dpp32((unsigned)v);
    unsigned hi = or_dpp32((unsigned)(v >> 32));
    unsigned slo = (unsigned)__builtin_amdgcn_readlane((int)lo, 63);
    unsigned shi = (unsigned)__builtin_amdgcn_readlane((int)hi, 63);
    return ((u64)shi << 32) | (u64)slo;
}

__global__ __launch_bounds__(64, 1)
void nms_kernel(const u64* __restrict__ maskT, const float* __restrict__ s_s,
                const int* __restrict__ order, const float* __restrict__ box,
                const int* __restrict__ nvalid_p, float* __restrict__ out) {
    const int lane = threadIdx.x;
    const int nv = *nvalid_p;
    const int nblk = (nv + 63) >> 6;
    int kcount = 0;
    int kp0 = 0, kp1 = 0, kp2 = 0, kp3 = 0;   // kept idx slots lane, 64+l, 128+l, 192+l
    u64 s1m = 0, s2m = 0, s2m_old = 0;

    Pipe A, B;
    A.col = A.s1 = A.s2 = A.g0 = A.g1 = A.g2 = A.g3 = 0; A.kc = 0;
    B.col = B.s1 = B.s2 = B.g0 = B.g1 = B.g2 = B.g3 = 0; B.kc = 0;

    if (nblk > 0) {
        // prologue: unconditional clamped loads (consume-side masks fix tails)
        const int nb1 = nblk - 1;
        {
            const int w1 = (1 < nb1) ? 1 : nb1, w2 = (2 < nb1) ? 2 : nb1;
            A.col = maskT[lane];
            A.s1  = maskT[(size_t)w1 * N + lane];
            A.s2  = maskT[(size_t)w2 * N + lane];
        }
        {
            const int bc = (1 < nb1) ? 1 : nb1;
            const int w1 = (2 < nb1) ? 2 : nb1, w2 = (3 < nb1) ? 3 : nb1;
            const int row = (bc << 6) + lane;
            B.col = maskT[(size_t)bc * N + row];
            B.s1  = maskT[(size_t)w1 * N + row];
            B.s2  = maskT[(size_t)w2 * N + row];
        }
    }

    auto step = [&](int b, Pipe& P) -> bool {
        // ---- consume (wait lands here; all masking is post-wait)
        u64 col = P.col;
        u64 s1v = (b + 1 < nblk) ? P.s1 : 0;
        u64 s2v = (b + 2 < nblk) ? P.s2 : 0;
        const int kcs = P.kc;
        u64 g0 = (lane < kcs)       ? P.g0 : 0;
        u64 g1 = (lane +  64 < kcs) ? P.g1 : 0;
        u64 g2 = (lane + 128 < kcs) ? P.g2 : 0;
        u64 g3 = (lane + 192 < kcs) ? P.g3 : 0;
        u64 x = g0 | g1 | g2 | g3 | s1m | s2m_old;

        // ---- reissue for b+2: ALL loads unconditional, clamped addresses
        {
            const int nb1 = nblk - 1;
            const int bc = (b + 2 < nb1) ? (b + 2) : nb1;
            const int w1 = (b + 3 < nb1) ? (b + 3) : nb1;
            const int w2 = (b + 4 < nb1) ? (b + 4) : nb1;
            const int row = (bc << 6) + lane;
            const u64* colw = maskT + (size_t)bc * N;
            P.col = colw[row];
            P.s1  = maskT[(size_t)w1 * N + row];
            P.s2  = maskT[(size_t)w2 * N + row];
            P.kc  = kcount;                       // snapshot: kept through b-1
            P.g0 = colw[kp0];                     // kp* default 0 -> always valid
            P.g1 = colw[kp1];
            P.g2 = colw[kp2];
            P.g3 = colw[kp3];
        }

        // ---- suppression word: DPP OR-reduce (VALU, no LDS)
        u64 rw = wave_or64(x);
        const int base = b << 6;
        const int rem = nv - base;
        u64 validm = (rem >= 64) ? ~0ull : ((1ull << rem) - 1ull);
        u64 todo = validm & ~rw;
        u64 km = 0;
        while (todo) {
            int l = (int)__builtin_ctzll(todo);
            u64 row_l = __ballot(((col >> l) & 1ull) != 0);  // in-tile row via symmetry
            const int pos = base + l;
            const bool own = (lane == (kcount & 63));
            const int slot = kcount >> 6;                    // uniform
            kp0 = (own && slot == 0) ? pos : kp0;
            kp1 = (own && slot == 1) ? pos : kp1;
            kp2 = (own && slot == 2) ? pos : kp2;
            kp3 = (own && slot == 3) ? pos : kp3;
            km |= (1ull << l);
            kcount++;
            // diagonal bit of row_l not guaranteed for degenerate tiny boxes
            todo &= ~(row_l | (1ull << l));
            if (kcount >= MAX_OUT) break;
        }
        u64 keepm = ((km >> lane) & 1ull) ? ~0ull : 0ull;
        s2m_old = s2m;
        s2m = s2v & keepm;
        s1m = s1v & keepm;
        return kcount < MAX_OUT;
    };

    bool run = true;
    for (int b = 0; run && b < nblk; b += 2) {
        run = step(b, A);
        if (run && b + 1 < nblk) run = step(b + 1, B);
    }

    // outputs: [score 256][box 256*16][valid 256], all float32
    float* out_score = out;
    float* out_box   = out + MAX_OUT;
    float* out_valid = out + MAX_OUT + MAX_OUT * 16;
    const float4* box4 = (const float4*)box;
    float4* ob4 = (float4*)out_box;
    #define EMIT_SLOT(Q, KP) do {                                              \
        const int t = lane + 64 * (Q);                                         \
        if (t < kcount) {                                                      \
            int p = (KP);                                                      \
            out_score[t] = s_s[p];                                             \
            out_valid[t] = 1.0f;                                               \
            int oi = order[p];                                                 \
            _Pragma("unroll")                                                  \
            for (int q = 0; q < 4; ++q) ob4[t * 4 + q] = box4[oi * 4 + q];     \
        } else {                                                               \
            out_score[t] = 0.0f;                                               \
            out_valid[t] = 0.0f;                                               \
            float4 z = make_float4(0.f, 0.f, 0.f, 0.f);                        \
            _Pragma("unroll")                                                  \
            for (int q = 0; q < 4; ++q) ob4[t * 4 + q] = z;                    \
        }                                                                      \
    } while (0)
    EMIT_SLOT(0, kp0);
    EMIT_SLOT(1, kp1);
    EMIT_SLOT(2, kp2);
    EMIT_SLOT(3, kp3);
    #undef EMIT_SLOT
}

extern "C" void kernel_launch(void* const* d_in, const int* in_sizes, int n_in,
                              void* d_out, int out_size, void* d_ws, size_t ws_size,
                              hipStream_t stream) {
    const float* score = (const float*)d_in[0];   // (8192,1) f32
    const float* box   = (const float*)d_in[1];   // (8192,16) f32
    char* ws = (char*)d_ws;
    u64*    maskT  = (u64*)ws;
    int*    order  = (int*)   (ws + MASK_BYTES);
    float*  s_s    = (float*) (ws + MASK_BYTES + 32768);
    float4* bbox   = (float4*)(ws + MASK_BYTES + 65536);
    float*  area   = (float*) (ws + MASK_BYTES + 65536 + 131072);
    int*    nvalid = (int*)   (ws + MASK_BYTES + 65536 + 131072 + 32768);

    rank_fused_kernel<<<256, 1024, 0, stream>>>(score, box, order, s_s, bbox, area, nvalid);
    mask_kernel<<<dim3(128, 32), 256, 0, stream>>>(bbox, area, nvalid, maskT);
    nms_kernel<<<1, 64, 0, stream>>>(maskT, s_s, order, box, nvalid, (float*)d_out);
}